// Round 3
// baseline (276.917 us; speedup 1.0000x reference)
//
#include <hip/hip_runtime.h>
#include <hip/hip_bf16.h>

// Dilate = 5x5 per-channel max filter, SAME padding, (64,384,384,3) f32.
// Vertical-streaming, LDS-free, barrier-free:
//   grid = 64 batch x 5 column-strips x 16 row-bands, 64-thread blocks (1 wave).
//   Each lane owns one float4-column (f4 col c = strip*64 + lane).
//   Stream down 28 input rows; per row: 5 overlapped coalesced float4 loads
//   (f4 cols c-2..c+2 -> consecutive lanes hit consecutive 16B, 4/5 L1 hits),
//   horizontal 5-max (channel stride 3 => static component taps), push into a
//   5-deep register ring; vertical 5-max; one coalesced float4 store per row.

#define Bn 64
#define H 384
#define W 384
#define C 3
#define ROWF (W * C)         // 1152 floats per image row
#define WF4 (ROWF / 4)       // 288 float4s per row
#define RB 24                // output rows per block
#define BANDS (H / RB)       // 16
#define STRIPS 5             // ceil(288/64) wave column strips
#define NEGINF (-3.402823466e+38f)

__device__ __forceinline__ float4 max4(float4 a, float4 b) {
  return make_float4(fmaxf(a.x, b.x), fmaxf(a.y, b.y),
                     fmaxf(a.z, b.z), fmaxf(a.w, b.w));
}

__global__ __launch_bounds__(64) void dilate5_kernel(
    const float* __restrict__ in, float* __restrict__ out) {
  const int tile = blockIdx.x;
  const int strip = tile % STRIPS;
  const int rest = tile / STRIPS;
  const int band = rest % BANDS;
  const int b = rest / BANDS;

  const int c = strip * 64 + threadIdx.x;   // f4 column this lane owns
  const int row0 = band * RB;
  const float* __restrict__ img = in + (size_t)b * H * ROWF;
  float* __restrict__ outimg = out + (size_t)b * H * ROWF;
  const bool active = (c < WF4);

  const float4 ninf = make_float4(NEGINF, NEGINF, NEGINF, NEGINF);
  const bool vA = (c - 2 >= 0) && (c - 2 < WF4);
  const bool vB = (c - 1 >= 0) && (c - 1 < WF4);
  const bool vC = (c < WF4);
  const bool vD = (c + 1 < WF4);
  const bool vE = (c + 2 < WF4);

  // load row gh, compute horizontal 5-max float4 for this lane's column
  auto hrow = [&](int gh) -> float4 {
    if (gh < 0 || gh >= H) return ninf;
    const float4* __restrict__ rp =
        reinterpret_cast<const float4*>(img + (size_t)gh * ROWF);
    float4 A = vA ? rp[c - 2] : ninf;
    float4 Bv = vB ? rp[c - 1] : ninf;
    float4 Cv = vC ? rp[c] : ninf;
    float4 D = vD ? rp[c + 1] : ninf;
    float4 E = vE ? rp[c + 2] : ninf;
    // out float j (0..3) = max of window floats (j+2 + 3t), window = A|B|C|D|E
    float4 h;
    h.x = fmaxf(fmaxf(fmaxf(A.z, Bv.y), fmaxf(Cv.x, Cv.w)), D.z);
    h.y = fmaxf(fmaxf(fmaxf(A.w, Bv.z), fmaxf(Cv.y, D.x)), D.w);
    h.z = fmaxf(fmaxf(fmaxf(Bv.x, Bv.w), fmaxf(Cv.z, D.y)), E.x);
    h.w = fmaxf(fmaxf(fmaxf(Bv.y, Cv.x), fmaxf(Cv.w, D.z)), E.y);
    return h;
  };

  // ring holds hmax of rows (o-2 .. o+1) at loop top for output row o
  float4 r0 = hrow(row0 - 2);
  float4 r1 = hrow(row0 - 1);
  float4 r2 = hrow(row0);
  float4 r3 = hrow(row0 + 1);

#pragma unroll 4
  for (int o = row0; o < row0 + RB; ++o) {
    float4 r4 = hrow(o + 2);
    float4 v = max4(max4(max4(r0, r1), max4(r2, r3)), r4);
    if (active)
      *reinterpret_cast<float4*>(outimg + (size_t)o * ROWF + 4 * c) = v;
    r0 = r1; r1 = r2; r2 = r3; r3 = r4;
  }
}

extern "C" void kernel_launch(void* const* d_in, const int* in_sizes, int n_in,
                              void* d_out, int out_size, void* d_ws, size_t ws_size,
                              hipStream_t stream) {
  const float* images = (const float*)d_in[0];
  float* out = (float*)d_out;
  const int nblocks = Bn * STRIPS * BANDS;  // 64*5*16 = 5120 (1 wave each)
  dilate5_kernel<<<nblocks, 64, 0, stream>>>(images, out);
}

// Round 4
// 212.089 us; speedup vs baseline: 1.3057x; 1.3057x over previous
//
#include <hip/hip_runtime.h>
#include <hip/hip_bf16.h>

// Dilate = 5x5 per-channel max filter, SAME padding, (64,384,384,3) f32.
// Vertical-streaming, LDS-free, branch-free inner loop, 1-row software prefetch.
//   grid = 64 batch x 6 band-groups x 5 column-strips; 256-thr blocks (4 waves).
//   Wave w of a block handles band group*4+w (RB=16 output rows, 20 input rows).
//   Lane owns f4-column c = strip*64 + lane. Per row: 5 coalesced float4 loads
//   (saddr + per-lane static voffset; addresses CLAMPED, boundary values fixed
//   via cndmask), horizontal 5-max in regs, 5-deep vertical ring, float4 store.

#define Bn 64
#define H 384
#define ROWF 1152            // floats per image row (384*3)
#define ROWBYTES (ROWF * 4)
#define WF4 288              // float4s per row
#define RB 16                // output rows per wave
#define GROUPS 6             // band-groups per image (24 bands / 4 waves)
#define STRIPS 5
#define NEGINF (-3.402823466e+38f)

__device__ __forceinline__ float4 max4(float4 a, float4 b) {
  return make_float4(fmaxf(a.x, b.x), fmaxf(a.y, b.y),
                     fmaxf(a.z, b.z), fmaxf(a.w, b.w));
}

struct Batch { float4 A, B, C, D, E; };

__global__ __launch_bounds__(256) void dilate5_kernel(
    const float* __restrict__ in, float* __restrict__ out) {
  const int wv = threadIdx.x >> 6;
  const int lane = threadIdx.x & 63;
  int t = blockIdx.x;
  const int strip = t % STRIPS; t /= STRIPS;
  const int grp = t % GROUPS;   t /= GROUPS;
  const int b = t;

  const int row0 = (grp * 4 + wv) * RB;
  const int c = strip * 64 + lane;          // owned f4 column
  const bool active = (c < WF4);
  const int cc = active ? c : (WF4 - 1);

  // clamped neighbor f4 columns (addresses always valid)
  const int cA = (cc - 2 >= 0) ? cc - 2 : 0;
  const int cB = (cc - 1 >= 0) ? cc - 1 : 0;
  const int cD = (cc + 1 < WF4) ? cc + 1 : WF4 - 1;
  const int cE = (cc + 2 < WF4) ? cc + 2 : WF4 - 1;
  const int offA = cA * 16, offB = cB * 16, offC = cc * 16,
            offD = cD * 16, offE = cE * 16;
  // value-validity masks (true image edges only)
  const bool mA = (c >= 2), mB = (c >= 1), mD = (c + 1 < WF4), mE = (c + 2 < WF4);
  const float4 ninf = make_float4(NEGINF, NEGINF, NEGINF, NEGINF);

  const char* __restrict__ imgb = (const char*)in + (size_t)b * H * ROWBYTES;
  char* __restrict__ outb = (char*)out + (size_t)b * H * ROWBYTES;

  auto loadrow = [&](int gh) -> Batch {
    int ghc = gh < 0 ? 0 : (gh > H - 1 ? H - 1 : gh);   // clamp address
    const char* rb = imgb + (size_t)ghc * ROWBYTES;
    Batch L;
    L.A = *reinterpret_cast<const float4*>(rb + offA);
    L.B = *reinterpret_cast<const float4*>(rb + offB);
    L.C = *reinterpret_cast<const float4*>(rb + offC);
    L.D = *reinterpret_cast<const float4*>(rb + offD);
    L.E = *reinterpret_cast<const float4*>(rb + offE);
    return L;
  };

  auto hcomb = [&](int gh, const Batch& L) -> float4 {
    float4 A  = mA ? L.A : ninf;
    float4 Bv = mB ? L.B : ninf;
    float4 Cv = L.C;
    float4 D  = mD ? L.D : ninf;
    float4 E  = mE ? L.E : ninf;
    float4 h;
    h.x = fmaxf(fmaxf(fmaxf(A.z, Bv.y), fmaxf(Cv.x, Cv.w)), D.z);
    h.y = fmaxf(fmaxf(fmaxf(A.w, Bv.z), fmaxf(Cv.y, D.x)), D.w);
    h.z = fmaxf(fmaxf(fmaxf(Bv.x, Bv.w), fmaxf(Cv.z, D.y)), E.x);
    h.w = fmaxf(fmaxf(fmaxf(Bv.y, Cv.x), fmaxf(Cv.w, D.z)), E.y);
    if (gh < 0 || gh >= H) h = ninf;   // uniform row-validity select
    return h;
  };

  // ring: hmax of rows o-2..o+1 at loop top for output row o
  float4 r0 = hcomb(row0 - 2, loadrow(row0 - 2));
  float4 r1 = hcomb(row0 - 1, loadrow(row0 - 1));
  float4 r2 = hcomb(row0,     loadrow(row0));
  float4 r3 = hcomb(row0 + 1, loadrow(row0 + 1));
  Batch Lc = loadrow(row0 + 2);        // prefetch for first iteration

#pragma unroll 4
  for (int i = 0; i < RB; ++i) {
    const int o = row0 + i;
    Batch Ln = loadrow(o + 3);         // prefetch next row (clamped past end)
    float4 r4 = hcomb(o + 2, Lc);
    float4 v = max4(max4(max4(r0, r1), max4(r2, r3)), r4);
    if (active)
      *reinterpret_cast<float4*>(outb + (size_t)o * ROWBYTES + offC) = v;
    r0 = r1; r1 = r2; r2 = r3; r3 = r4;
    Lc = Ln;
  }
}

extern "C" void kernel_launch(void* const* d_in, const int* in_sizes, int n_in,
                              void* d_out, int out_size, void* d_ws, size_t ws_size,
                              hipStream_t stream) {
  const float* images = (const float*)d_in[0];
  float* out = (float*)d_out;
  const int nblocks = Bn * GROUPS * STRIPS;  // 64*6*5 = 1920
  dilate5_kernel<<<nblocks, 256, 0, stream>>>(images, out);
}